// Round 4
// baseline (1192.358 us; speedup 1.0000x reference)
//
#include <hip/hip_runtime.h>
#include <stdint.h>

// Problem constants (from reference)
#define N_USERS 100000
#define N_ITEMS 50000
#define N_NODES 150000
#define NNZ     4800000
#define DIM     64
#define NELEM   (N_NODES * DIM)   // 9,600,000
#define EPS_F   0.1f

// Invariants established in rounds 0-12:
//  - all inputs f32; outputs f32; out = [all_mean | layer_embeddings]
//  - noise bits = o0 ^ o1 of threefry2x32(fold_in(key42,k), (0, flat_idx));
//    u = bitcast((bits>>9)|0x3f800000) - 1
//  - SpMM must accumulate per-row in ASCENDING EDGE ORDER with separate
//    __fmul_rn/__fadd_rn (matches np f32 sequential scatter-add; sign()
//    amplifies any reassociation into 0.02-scale errors)
//  - R10/R12: hops scalarized (readfirstlane -> s_load pair stream);
//    VALUBusy 73->35%, dur 198->191: hops are gather-miss bound
//    (587 MB L2-fill/hop of x-row traffic, ~51% L2 hit), NOT VALU/BW.
//  - R13 (this round): front-end is ~374us vs ~70us ideal; suspect =
//    scatter's 8B stores sprayed over 41MB bucket regions (cross-XCD
//    partial-line handoff). Rewrite: chunk-major staging (each block
//    writes only its own 128KB window; tickets from LDS counting sort),
//    group_sort gathers per-bucket runs via two tiny scans. Final pairs
//    bit-identical (rank-sort by edge id canonicalizes run race).
//    Hops: unroll 8->16 as MSHR-vs-ILP probe.

#define NBUCK  768     // row buckets
#define RPB    196     // rows per bucket (768*196 = 150,528 >= 150,000)
#define BCAP   6752    // LDS cap / pairsF stride per bucket (mean 6250, +6.3 sigma)
#define CHUNK  16384   // edges per chunk block
#define NCHUNK 293     // ceil(NNZ / CHUNK); 292*16384=4,784,128, last=15,872

// entry packing: e[0:23) | col[23:41) | lrow[41:49)
#define E_MASK   0x7FFFFFu
#define COL_MASK 0x3FFFFu

typedef unsigned long long ull;

// ---------------------------------------------------------------------------
// JAX threefry2x32
// ---------------------------------------------------------------------------
__host__ __device__ inline void threefry2x32_fn(unsigned k0, unsigned k1,
                                                unsigned x0, unsigned x1,
                                                unsigned* o0, unsigned* o1) {
  unsigned ks0 = k0, ks1 = k1, ks2 = k0 ^ k1 ^ 0x1BD11BDAu;
  x0 += ks0; x1 += ks1;
#define TF_ROUND(r) { x0 += x1; x1 = (x1 << (r)) | (x1 >> (32 - (r))); x1 ^= x0; }
  TF_ROUND(13) TF_ROUND(15) TF_ROUND(26) TF_ROUND(6)
  x0 += ks1; x1 += ks2 + 1u;
  TF_ROUND(17) TF_ROUND(29) TF_ROUND(16) TF_ROUND(24)
  x0 += ks2; x1 += ks0 + 2u;
  TF_ROUND(13) TF_ROUND(15) TF_ROUND(26) TF_ROUND(6)
  x0 += ks0; x1 += ks1 + 3u;
  TF_ROUND(17) TF_ROUND(29) TF_ROUND(16) TF_ROUND(24)
  x0 += ks1; x1 += ks2 + 4u;
  TF_ROUND(13) TF_ROUND(15) TF_ROUND(26) TF_ROUND(6)
  x0 += ks2; x1 += ks0 + 5u;
#undef TF_ROUND
  *o0 = x0; *o1 = x1;
}

// ---------------------------------------------------------------------------
// K1: per-(chunk,bucket) histogram via LDS counters. counts[c*NBUCK + b].
// ---------------------------------------------------------------------------
__global__ void hist_kernel(const int* __restrict__ rows,
                            int* __restrict__ counts) {
  __shared__ int h[NBUCK];
  int c = blockIdx.x, tid = threadIdx.x;
  for (int t = tid; t < NBUCK; t += 256) h[t] = 0;
  __syncthreads();
  int cb = c * CHUNK;
  #pragma unroll 4
  for (int k = 0; k < CHUNK / 256; ++k) {
    int i = cb + k * 256 + tid;
    if (i < NNZ) {
      int r = rows[i];
      atomicAdd(&h[r / RPB], 1);
    }
  }
  __syncthreads();
  for (int t = tid; t < NBUCK; t += 256)
    counts[c * NBUCK + t] = h[t];
}

// ---------------------------------------------------------------------------
// K2a: per-bucket exclusive prefix over chunks (768 threads = 3 blocks).
// base[c*NBUCK + b] = position of chunk c's run within bucket b's LDS image.
// ---------------------------------------------------------------------------
__global__ void scanB_kernel(const int* __restrict__ counts,
                             int* __restrict__ base,
                             int* __restrict__ btot) {
  int b = blockIdx.x * 256 + threadIdx.x;   // 0..767 exact
  int run = 0;
  #pragma unroll 8
  for (int c = 0; c < NCHUNK; ++c) {
    int v = counts[c * NBUCK + b];
    base[c * NBUCK + b] = run;
    run += v;
  }
  btot[b] = run;
}

// ---------------------------------------------------------------------------
// K2b: per-chunk exclusive prefix over buckets (one wave per chunk).
// off2[c*NBUCK + b] = global slot in staging2 where chunk c's bucket-b run
// starts (= c*CHUNK + sum_{b'<b} counts[c][b']). Partitions each chunk
// window exactly (sum of counts over b == chunk edge count).
// ---------------------------------------------------------------------------
__global__ void scanC_kernel(const int* __restrict__ counts,
                             int* __restrict__ off2) {
  int wid = threadIdx.x >> 6, lane = threadIdx.x & 63;
  int c = blockIdx.x * 4 + wid;
  if (c >= NCHUNK) return;
  const int* cc = counts + c * NBUCK;
  int* oo = off2 + c * NBUCK;
  int loc[12];
  int sum = 0;
  #pragma unroll
  for (int j = 0; j < 12; ++j) {          // 768 = 64 lanes * 12
    int v = cc[lane * 12 + j];
    loc[j] = sum; sum += v;
  }
  int pref = 0;                           // exclusive prefix of lane sums
  for (int k = 0; k < 64; ++k) {
    int sk = __shfl(sum, k, 64);
    if (k < lane) pref += sk;
  }
  int base0 = c * CHUNK + pref;
  #pragma unroll
  for (int j = 0; j < 12; ++j)
    oo[lane * 12 + j] = base0 + loc[j];
}

// ---------------------------------------------------------------------------
// K3: chunk-local counting scatter. Each block owns a contiguous 128 KB
// window of staging2 (its chunk); entries are placed at
// off2[c][b] + LDS-ticket. All partial cache lines complete within one
// block's L2 residency -> no cross-XCD handoff, near-ideal write traffic.
// Run order within (c,b) is racy -- canonicalized by K4's edge-id sort.
// ---------------------------------------------------------------------------
__global__ void scatter_kernel(const int* __restrict__ rows,
                               const int* __restrict__ cols,
                               const int* __restrict__ off2,
                               ull* __restrict__ staging2) {
  __shared__ int obase[NBUCK];
  __shared__ int cur[NBUCK];
  int c = blockIdx.x, tid = threadIdx.x;
  for (int t = tid; t < NBUCK; t += 256) {
    obase[t] = off2[c * NBUCK + t];
    cur[t] = 0;
  }
  __syncthreads();
  int cb = c * CHUNK;
  #pragma unroll 4
  for (int k = 0; k < CHUNK / 256; ++k) {
    int i = cb + k * 256 + tid;
    if (i < NNZ) {
      int r  = rows[i];
      int cc = cols[i];
      int b  = r / RPB;
      int lr = r - b * RPB;
      int p  = atomicAdd(&cur[b], 1);     // ticket within (chunk,bucket); no cap
      staging2[obase[b] + p] =            // needed: hist counted these exact edges
          ((ull)(unsigned)lr << 41) | ((ull)(unsigned)cc << 23) | (unsigned)i;
    }
  }
}

// ---------------------------------------------------------------------------
// K4: one block per bucket. Gather the bucket's 293 runs from staging2 into
// LDS B (coalesced reads; positions from base/off2), then: count rows ->
// scan -> group by row into B2 -> rank-sort each row by edge id (ascending;
// preserves the load-bearing accumulation order) -> gather vals[e] -> write
// final (col<<32)|val pairs to pairsF in bucketed-CSR layout. cnt/off out.
// ---------------------------------------------------------------------------
__global__ void group_sort_kernel(const float* __restrict__ vals,
                                  const int* __restrict__ counts,
                                  const int* __restrict__ base,
                                  const int* __restrict__ off2,
                                  const int* __restrict__ btot,
                                  const ull* __restrict__ staging2,
                                  ull* __restrict__ pairsF,
                                  int* __restrict__ cnt,
                                  int* __restrict__ off) {
  __shared__ ull B[BCAP];                  // 54,016 B
  __shared__ ull B2[BCAP];                 // 54,016 B
  __shared__ int rowcnt[RPB];
  __shared__ int rowoff[RPB + 1];
  __shared__ int rowcur[RPB];
  int b = blockIdx.x, tid = threadIdx.x;
  int wid = tid >> 6, lane = tid & 63;

  for (int t = tid; t < RPB; t += 256) { rowcnt[t] = 0; rowcur[t] = 0; }

  // Fill: each wave walks chunks round-robin; run params are wave-uniform
  for (int c = wid; c < NCHUNK; c += 4) {
    int len  = counts[c * NBUCK + b];
    int src  = off2[c * NBUCK + b];
    int dstB = base[c * NBUCK + b];
    for (int j = lane; j < len; j += 64)
      if (dstB + j < BCAP)                 // btot overflow guard (P ~ 1e-10)
        B[dstB + j] = staging2[src + j];
  }
  __syncthreads();

  int tot = btot[b]; if (tot > BCAP) tot = BCAP;

  // Phase A: per-row counts
  for (int s = tid; s < tot; s += 256)
    atomicAdd(&rowcnt[(int)(B[s] >> 41)], 1);
  __syncthreads();

  // Phase B: exclusive scan over 196 rows (serial; trivial vs block work)
  if (tid == 0) {
    int run = 0;
    for (int t = 0; t < RPB; ++t) { rowoff[t] = run; run += rowcnt[t]; }
    rowoff[RPB] = run;
  }
  __syncthreads();

  // cnt/off for this bucket's rows
  int row0 = b * RPB;
  for (int t = tid; t < RPB; t += 256) {
    int r = row0 + t;
    if (r < N_NODES) { cnt[r] = rowcnt[t]; off[r] = b * BCAP + rowoff[t]; }
  }

  // Phase C: group entries by row into B2 (order within row still racy)
  for (int s = tid; s < tot; s += 256) {
    ull v = B[s];
    int lr = (int)(v >> 41);
    int p = atomicAdd(&rowcur[lr], 1);
    B2[rowoff[lr] + p] = v;
  }
  __syncthreads();

  // Phase D: rank by edge id within row (unique e -> bijection), gather val,
  // write final pair at its sorted slot in pairsF.
  for (int s = tid; s < tot; s += 256) {
    ull v = B2[s];
    int lr = (int)(v >> 41);
    unsigned e = (unsigned)(v & E_MASK);
    int lo = rowoff[lr], hi = rowoff[lr + 1];
    int rk = 0;
    for (int j = lo; j < hi; ++j)
      rk += ((unsigned)(B2[j] & E_MASK) < e) ? 1 : 0;
    float val = vals[e];                   // one-time random gather (L3-hot)
    unsigned col = (unsigned)((v >> 23) & COL_MASK);
    pairsF[(long long)b * BCAP + lo + rk] = ((ull)col << 32) | __float_as_uint(val);
  }
}

// ---------------------------------------------------------------------------
// K5-7: fused SpMM + noise + output epilogue, scalarized pair stream.
// One wave per row, lane = dim. row/cnt/off uniform via readfirstlane so
// pair reads lower to s_load; gathers are global_load_dword v, s[base].
// 16 gathers in flight (MSHR/ILP probe); indices uniformly clamped to d-1
// with invalid vals zeroed (adding +0.0 is exact) -> no serial tail.
// Strict ascending-edge __fadd_rn chain intact.
// ---------------------------------------------------------------------------
template <int K>
__global__ void spmm_noise_kernel(const ull* __restrict__ pairs,
                                  const int* __restrict__ cnt,
                                  const int* __restrict__ off,
                                  const float* __restrict__ user_e,
                                  const float* __restrict__ item_e,
                                  const float* __restrict__ src,
                                  float* __restrict__ dst,
                                  float* __restrict__ out_mean,
                                  unsigned key0, unsigned key1) {
  int wid  = threadIdx.x >> 6;
  int lane = threadIdx.x & 63;
  int row  = blockIdx.x * 4 + wid;          // grid covers N_NODES exactly
  int row_u = __builtin_amdgcn_readfirstlane(row);   // wave-uniform SGPR
  int d = cnt[row_u];                       // uniform -> s_load
  if (d > 128) d = 128;                     // realized max deg ~70
  const ull* prow = pairs + off[row_u];     // uniform SGPR base

  #define GATHER(c, xout_) do {                                            \
    if (K == 0) {                                                          \
      const float* bp_ = ((c) < N_USERS)                                   \
          ? user_e + (long long)(c) * DIM                                  \
          : item_e + (long long)((c) - N_USERS) * DIM;                     \
      xout_ = bp_[lane];                                                   \
    } else {                                                               \
      xout_ = src[(long long)(c) * DIM + lane];                            \
    }                                                                      \
  } while (0)

  float acc = 0.0f;
  for (int t = 0; t < d; t += 16) {         // clamped reads stay in [off, off+d)
    int dm1 = d - 1;
    ull p[16];
    #pragma unroll
    for (int j = 0; j < 16; ++j) {
      int i = t + j; if (i > dm1) i = dm1;
      p[j] = prow[i];                       // uniform -> s_load_dwordx2
    }
    float x[16];
    #pragma unroll
    for (int j = 0; j < 16; ++j) {
      int c = (int)(unsigned)(p[j] >> 32);
      GATHER(c, x[j]);
    }
    #pragma unroll
    for (int j = 0; j < 16; ++j) {
      float v = (t + j < d) ? __uint_as_float((unsigned)(p[j] & 0xffffffffu)) : 0.0f;
      // strict ascending edge order; v==0 lanes add exact +0.0 (x finite)
      acc = __fadd_rn(acc, __fmul_rn(v, x[j]));
    }
  }
  #undef GATHER

  // --- noise epilogue (exact JAX stream; norm association not load-bearing)
  int i = row * DIM + lane;
  unsigned o0, o1;
  threefry2x32_fn(key0, key1, 0u, (unsigned)i, &o0, &o1);
  unsigned bits = o0 ^ o1;
  float u = __uint_as_float((bits >> 9) | 0x3f800000u) - 1.0f;
  float ss = __fmul_rn(u, u);
  #pragma unroll
  for (int offs = 32; offs >= 1; offs >>= 1)
    ss += __shfl_xor(ss, offs, 64);
  float noise = u / sqrtf(ss);
  float s = (acc > 0.0f) ? 1.0f : ((acc < 0.0f) ? -1.0f : 0.0f);
  float val = __fadd_rn(acc, __fmul_rn(s, __fmul_rn(noise, EPS_F)));

  if (K == 0) {
    dst[i] = val;                           // dst == out_layer (hop-0 ego)
    out_mean[i] = val;
  } else if (K == 1) {
    dst[i] = val;                           // ws ego buffer for hop 2
    out_mean[i] = __fadd_rn(out_mean[i], val);
  } else {
    out_mean[i] = __fadd_rn(out_mean[i], val) / 3.0f;
  }
}

// ---------------------------------------------------------------------------
// Launch
// ---------------------------------------------------------------------------
extern "C" void kernel_launch(void* const* d_in, const int* in_sizes, int n_in,
                              void* d_out, int out_size, void* d_ws, size_t ws_size,
                              hipStream_t stream) {
  const float* user_e = (const float*)d_in[0];
  const float* item_e = (const float*)d_in[1];
  const int*   rows   = (const int*)d_in[2];
  const int*   cols   = (const int*)d_in[3];
  const float* vals   = (const float*)d_in[4];

  float* out_mean  = (float*)d_out;           // [all_mean: 150000 x 64]
  float* out_layer = (float*)d_out + NELEM;   // [layer_embeddings] == hop-0 ego

  // workspace layout (83.8 MB total; ego aliases dead staging2):
  //   staging2 38,404,096 | pairsF 41,484,288 | counts 900,096 |
  //   base 900,096 | off2 900,096 | btot 3,072 | cnt 600,000 | off 600,000
  char* w = (char*)d_ws;
  ull*   staging2 = (ull*)w;                          // [0, 38,404,096)
  ull*   pairsF   = (ull*)(w + 38404096);             // 41,484,288
  int*   counts   = (int*)(w + 79888384);             // 900,096
  int*   basep    = (int*)(w + 80788480);             // 900,096
  int*   off2     = (int*)(w + 81688576);             // 900,096
  int*   btot     = (int*)(w + 82588672);             // 3,072
  int*   cnt      = (int*)(w + 82591744);             // 600,000
  int*   off      = (int*)(w + 83191744);             // 600,000
  float* ego      = (float*)w;                        // alias staging2 (dead after K4)

  // fold_in(key(42), k) = threefry((0,42),(0,k))
  unsigned hk0[3], hk1[3];
  for (int k = 0; k < 3; ++k)
    threefry2x32_fn(0u, 42u, 0u, (unsigned)k, &hk0[k], &hk1[k]);

  const int BT = 256;
  const unsigned row_blocks = N_NODES / 4;    // 37500 exact (4 rows/block)

  hist_kernel<<<NCHUNK, BT, 0, stream>>>(rows, counts);
  scanB_kernel<<<NBUCK / BT, BT, 0, stream>>>(counts, basep, btot);
  scanC_kernel<<<(NCHUNK + 3) / 4, BT, 0, stream>>>(counts, off2);
  scatter_kernel<<<NCHUNK, BT, 0, stream>>>(rows, cols, off2, staging2);
  group_sort_kernel<<<NBUCK, BT, 0, stream>>>(vals, counts, basep, off2, btot,
                                              staging2, pairsF, cnt, off);

  spmm_noise_kernel<0><<<row_blocks, BT, 0, stream>>>(
      pairsF, cnt, off, user_e, item_e, nullptr, out_layer, out_mean, hk0[0], hk1[0]);
  spmm_noise_kernel<1><<<row_blocks, BT, 0, stream>>>(
      pairsF, cnt, off, nullptr, nullptr, out_layer, ego, out_mean, hk0[1], hk1[1]);
  spmm_noise_kernel<2><<<row_blocks, BT, 0, stream>>>(
      pairsF, cnt, off, nullptr, nullptr, ego, nullptr, out_mean, hk0[2], hk1[2]);
}

// Round 5
// 910.027 us; speedup vs baseline: 1.3102x; 1.3102x over previous
//
#include <hip/hip_runtime.h>
#include <stdint.h>

// Problem constants (from reference)
#define N_USERS 100000
#define N_ITEMS 50000
#define N_NODES 150000
#define NNZ     4800000
#define DIM     64
#define NELEM   (N_NODES * DIM)   // 9,600,000
#define EPS_F   0.1f

// Invariants established in rounds 0-13:
//  - all inputs f32; outputs f32; out = [all_mean | layer_embeddings]
//  - noise bits = o0 ^ o1 of threefry2x32(fold_in(key42,k), (0, flat_idx));
//    u = bitcast((bits>>9)|0x3f800000) - 1
//  - SpMM must accumulate per-row in ASCENDING EDGE ORDER with separate
//    __fmul_rn/__fadd_rn (matches np f32 sequential scatter-add)
//  - R10/R12: hops scalarized (readfirstlane -> s_load pair stream);
//    VALUBusy 73->35%, dur 198->191: hops are gather-miss bound, not VALU.
//  - R13 POST-MORTEM (regression 947->1192): chunk-major staging made
//    group_sort read ~170B runs from 293 windows -> 7.5x cross-XCD FETCH
//    amplification (288MB), and B+B2 = 108KB LDS -> 1 block/CU -> 11%
//    occupancy -> 388us. LESSON: scattered fire-and-forget WRITES are
//    survivable; scattered cross-XCD READS + giant LDS are not.
//  - R14 (this round): revert to R1 shape (bucket-major scatter, in-place
//    single-B group_sort), fix group_sort occupancy by shrinking buckets
//    4x: NBUCK 3072 / RPB 49 / BCAP 1856 -> 15.4KB LDS -> 8 blocks/CU.
//    spmm = exact R3-measured unroll-8 body (191us).

#define NBUCK  3072    // row buckets
#define RPB    49      // rows per bucket (3072*49 = 150,528 >= 150,000)
#define BCAP   1856    // entry cap per bucket (mean 1562.5, +7.4 sigma)
#define CHUNK  8192    // edges per chunk block
#define NCHUNK 586     // ceil(NNZ / CHUNK); 585*8192=4,792,320, last=7,680

// entry packing: e[0:23) | col[23:41) | lrow[41:47)
#define E_MASK   0x7FFFFFu
#define COL_MASK 0x3FFFFu

typedef unsigned long long ull;

// ---------------------------------------------------------------------------
// JAX threefry2x32
// ---------------------------------------------------------------------------
__host__ __device__ inline void threefry2x32_fn(unsigned k0, unsigned k1,
                                                unsigned x0, unsigned x1,
                                                unsigned* o0, unsigned* o1) {
  unsigned ks0 = k0, ks1 = k1, ks2 = k0 ^ k1 ^ 0x1BD11BDAu;
  x0 += ks0; x1 += ks1;
#define TF_ROUND(r) { x0 += x1; x1 = (x1 << (r)) | (x1 >> (32 - (r))); x1 ^= x0; }
  TF_ROUND(13) TF_ROUND(15) TF_ROUND(26) TF_ROUND(6)
  x0 += ks1; x1 += ks2 + 1u;
  TF_ROUND(17) TF_ROUND(29) TF_ROUND(16) TF_ROUND(24)
  x0 += ks2; x1 += ks0 + 2u;
  TF_ROUND(13) TF_ROUND(15) TF_ROUND(26) TF_ROUND(6)
  x0 += ks0; x1 += ks1 + 3u;
  TF_ROUND(17) TF_ROUND(29) TF_ROUND(16) TF_ROUND(24)
  x0 += ks1; x1 += ks2 + 4u;
  TF_ROUND(13) TF_ROUND(15) TF_ROUND(26) TF_ROUND(6)
  x0 += ks2; x1 += ks0 + 5u;
#undef TF_ROUND
  *o0 = x0; *o1 = x1;
}

// ---------------------------------------------------------------------------
// K1: per-(chunk,bucket) histogram via LDS counters. counts[c*NBUCK + b].
// ---------------------------------------------------------------------------
__global__ void hist_kernel(const int* __restrict__ rows,
                            int* __restrict__ counts) {
  __shared__ int h[NBUCK];                 // 12 KB
  int c = blockIdx.x, tid = threadIdx.x;
  for (int t = tid; t < NBUCK; t += 256) h[t] = 0;
  __syncthreads();
  int cb = c * CHUNK;
  #pragma unroll 4
  for (int k = 0; k < CHUNK / 256; ++k) {
    int i = cb + k * 256 + tid;
    if (i < NNZ) {
      int r = rows[i];
      atomicAdd(&h[r / RPB], 1);
    }
  }
  __syncthreads();
  for (int t = tid; t < NBUCK; t += 256)
    counts[c * NBUCK + t] = h[t];
}

// ---------------------------------------------------------------------------
// K2: per-bucket exclusive prefix over chunks (3072 threads = 12 blocks).
// base[c*NBUCK + b] = start slot of chunk c's entries within bucket b.
// Reads are coalesced per c-iteration (lanes span consecutive b).
// ---------------------------------------------------------------------------
__global__ void scan_kernel(const int* __restrict__ counts,
                            int* __restrict__ base,
                            int* __restrict__ btot) {
  int b = blockIdx.x * 256 + threadIdx.x;   // 0..3071 exact
  int run = 0;
  #pragma unroll 8
  for (int c = 0; c < NCHUNK; ++c) {
    int v = counts[c * NBUCK + b];
    base[c * NBUCK + b] = run;
    run += v;
  }
  btot[b] = run;
}

// ---------------------------------------------------------------------------
// K3: deterministic-range scatter (bucket-major). Each chunk block preloads
// its per-bucket slot bases into LDS, appends packed (lrow|col|e) entries.
// Stores are scattered 8B but fire-and-forget (bandwidth, not latency) --
// measured survivable in R12. Order within a (chunk,bucket) range is racy;
// canonicalized by K4's edge-id rank-sort.
// ---------------------------------------------------------------------------
__global__ void scatter_kernel(const int* __restrict__ rows,
                               const int* __restrict__ cols,
                               const int* __restrict__ base,
                               ull* __restrict__ staging) {
  __shared__ int cur[NBUCK];               // 12 KB
  int c = blockIdx.x, tid = threadIdx.x;
  for (int t = tid; t < NBUCK; t += 256) cur[t] = base[c * NBUCK + t];
  __syncthreads();
  int cb = c * CHUNK;
  #pragma unroll 4
  for (int k = 0; k < CHUNK / 256; ++k) {
    int i = cb + k * 256 + tid;
    if (i < NNZ) {
      int r  = rows[i];
      int cc = cols[i];
      int b  = r / RPB;
      int lr = r - b * RPB;
      int p  = atomicAdd(&cur[b], 1);
      if (p < BCAP)
        staging[(long long)b * BCAP + p] =
            ((ull)(unsigned)lr << 41) | ((ull)(unsigned)cc << 23) | (unsigned)i;
    }
  }
}

// ---------------------------------------------------------------------------
// K4: one block per bucket (3072 blocks). LDS = 15.4 KB -> 8 blocks/CU
// (32 waves): 4x the latency hiding of the R9 768-bucket version.
// Count rows -> scan (49 iters) -> group by row into LDS B -> rank-sort
// each row by edge id (ascending; preserves the load-bearing accumulation
// order) -> gather vals[e] -> overwrite staging in place with final
// (col<<32)|val pairs in bucketed-CSR layout. Writes cnt/off.
// ---------------------------------------------------------------------------
__global__ void group_sort_kernel(const float* __restrict__ vals,
                                  const int* __restrict__ btot,
                                  ull* __restrict__ staging,
                                  int* __restrict__ cnt,
                                  int* __restrict__ off) {
  __shared__ ull B[BCAP];                  // 14,848 B
  __shared__ int rowcnt[RPB];
  __shared__ int rowoff[RPB + 1];
  __shared__ int rowcur[RPB];
  int b = blockIdx.x, tid = threadIdx.x;
  int tot = btot[b]; if (tot > BCAP) tot = BCAP;
  ull* sg = staging + (long long)b * BCAP;

  for (int t = tid; t < RPB; t += 256) { rowcnt[t] = 0; rowcur[t] = 0; }
  __syncthreads();

  // Phase A: per-row counts (staging read 1; bucket region is L2-hot)
  for (int s = tid; s < tot; s += 256) {
    ull v = sg[s];
    atomicAdd(&rowcnt[(int)(v >> 41)], 1);
  }
  __syncthreads();

  // Phase B: exclusive scan over 49 rows (serial; trivial)
  if (tid == 0) {
    int run = 0;
    for (int t = 0; t < RPB; ++t) { rowoff[t] = run; run += rowcnt[t]; }
    rowoff[RPB] = run;
  }
  __syncthreads();

  // cnt/off for this bucket's rows
  int row0 = b * RPB;
  for (int t = tid; t < RPB; t += 256) {
    int r = row0 + t;
    if (r < N_NODES) { cnt[r] = rowcnt[t]; off[r] = b * BCAP + rowoff[t]; }
  }

  // Phase C: group entries by row into B (order within row still racy)
  for (int s = tid; s < tot; s += 256) {
    ull v = sg[s];
    int lr = (int)(v >> 41);
    int p = atomicAdd(&rowcur[lr], 1);
    B[rowoff[lr] + p] = v;
  }
  __syncthreads();

  // Phase D: rank by edge id within row (unique e -> bijection), gather val,
  // write final pair at its sorted slot. In-place over staging is safe:
  // all sg reads completed in Phase C (barrier above).
  for (int s = tid; s < tot; s += 256) {
    ull v = B[s];
    int lr = (int)(v >> 41);
    unsigned e = (unsigned)(v & E_MASK);
    int lo = rowoff[lr], hi = rowoff[lr + 1];
    int rk = 0;
    for (int j = lo; j < hi; ++j)
      rk += ((unsigned)(B[j] & E_MASK) < e) ? 1 : 0;
    float val = vals[e];                   // one-time random gather (L3-hot)
    unsigned col = (unsigned)((v >> 23) & COL_MASK);
    sg[lo + rk] = ((ull)col << 32) | __float_as_uint(val);
  }
}

// ---------------------------------------------------------------------------
// K5-7: fused SpMM + noise + output epilogue, scalarized pair stream.
// EXACT R3-measured body (191us/hop): one wave per row, lane = dim;
// row/cnt/off uniform via readfirstlane -> s_load pair reads; 8 gathers in
// flight, indices uniformly clamped to d-1 with invalid vals zeroed
// (adding +0.0 is exact) -> no serial tail. Strict ascending-edge chain.
// ---------------------------------------------------------------------------
template <int K>
__global__ void spmm_noise_kernel(const ull* __restrict__ pairs,
                                  const int* __restrict__ cnt,
                                  const int* __restrict__ off,
                                  const float* __restrict__ user_e,
                                  const float* __restrict__ item_e,
                                  const float* __restrict__ src,
                                  float* __restrict__ dst,
                                  float* __restrict__ out_mean,
                                  unsigned key0, unsigned key1) {
  int wid  = threadIdx.x >> 6;
  int lane = threadIdx.x & 63;
  int row  = blockIdx.x * 4 + wid;          // grid covers N_NODES exactly
  int row_u = __builtin_amdgcn_readfirstlane(row);   // wave-uniform SGPR
  int d = cnt[row_u];                       // uniform -> s_load
  if (d > 128) d = 128;                     // realized max deg ~70
  const ull* prow = pairs + off[row_u];     // uniform SGPR base

  #define GATHER(c, xout_) do {                                            \
    if (K == 0) {                                                          \
      const float* bp_ = ((c) < N_USERS)                                   \
          ? user_e + (long long)(c) * DIM                                  \
          : item_e + (long long)((c) - N_USERS) * DIM;                     \
      xout_ = bp_[lane];                                                   \
    } else {                                                               \
      xout_ = src[(long long)(c) * DIM + lane];                            \
    }                                                                      \
  } while (0)

  float acc = 0.0f;
  for (int t = 0; t < d; t += 8) {          // d>=1 whenever loop runs
    int i0 = t,     i1 = t + 1, i2 = t + 2, i3 = t + 3;
    int i4 = t + 4, i5 = t + 5, i6 = t + 6, i7 = t + 7;
    int dm1 = d - 1;
    if (i1 > dm1) i1 = dm1;  if (i2 > dm1) i2 = dm1;  if (i3 > dm1) i3 = dm1;
    if (i4 > dm1) i4 = dm1;  if (i5 > dm1) i5 = dm1;  if (i6 > dm1) i6 = dm1;
    if (i7 > dm1) i7 = dm1;
    ull p0 = prow[i0], p1 = prow[i1], p2 = prow[i2], p3 = prow[i3];
    ull p4 = prow[i4], p5 = prow[i5], p6 = prow[i6], p7 = prow[i7];
    int c0 = (int)(unsigned)(p0 >> 32), c1 = (int)(unsigned)(p1 >> 32);
    int c2 = (int)(unsigned)(p2 >> 32), c3 = (int)(unsigned)(p3 >> 32);
    int c4 = (int)(unsigned)(p4 >> 32), c5 = (int)(unsigned)(p5 >> 32);
    int c6 = (int)(unsigned)(p6 >> 32), c7 = (int)(unsigned)(p7 >> 32);
    float x0, x1, x2, x3, x4, x5, x6, x7;
    GATHER(c0, x0); GATHER(c1, x1); GATHER(c2, x2); GATHER(c3, x3);
    GATHER(c4, x4); GATHER(c5, x5); GATHER(c6, x6); GATHER(c7, x7);
    float v0 = __uint_as_float((unsigned)(p0 & 0xffffffffu));
    float v1 = (t + 1 < d) ? __uint_as_float((unsigned)(p1 & 0xffffffffu)) : 0.0f;
    float v2 = (t + 2 < d) ? __uint_as_float((unsigned)(p2 & 0xffffffffu)) : 0.0f;
    float v3 = (t + 3 < d) ? __uint_as_float((unsigned)(p3 & 0xffffffffu)) : 0.0f;
    float v4 = (t + 4 < d) ? __uint_as_float((unsigned)(p4 & 0xffffffffu)) : 0.0f;
    float v5 = (t + 5 < d) ? __uint_as_float((unsigned)(p5 & 0xffffffffu)) : 0.0f;
    float v6 = (t + 6 < d) ? __uint_as_float((unsigned)(p6 & 0xffffffffu)) : 0.0f;
    float v7 = (t + 7 < d) ? __uint_as_float((unsigned)(p7 & 0xffffffffu)) : 0.0f;
    // strict ascending edge order; v==0 lanes add exact +0.0 (x finite)
    acc = __fadd_rn(acc, __fmul_rn(v0, x0));
    acc = __fadd_rn(acc, __fmul_rn(v1, x1));
    acc = __fadd_rn(acc, __fmul_rn(v2, x2));
    acc = __fadd_rn(acc, __fmul_rn(v3, x3));
    acc = __fadd_rn(acc, __fmul_rn(v4, x4));
    acc = __fadd_rn(acc, __fmul_rn(v5, x5));
    acc = __fadd_rn(acc, __fmul_rn(v6, x6));
    acc = __fadd_rn(acc, __fmul_rn(v7, x7));
  }
  #undef GATHER

  // --- noise epilogue (exact JAX stream; norm association not load-bearing)
  int i = row * DIM + lane;
  unsigned o0, o1;
  threefry2x32_fn(key0, key1, 0u, (unsigned)i, &o0, &o1);
  unsigned bits = o0 ^ o1;
  float u = __uint_as_float((bits >> 9) | 0x3f800000u) - 1.0f;
  float ss = __fmul_rn(u, u);
  #pragma unroll
  for (int offs = 32; offs >= 1; offs >>= 1)
    ss += __shfl_xor(ss, offs, 64);
  float noise = u / sqrtf(ss);
  float s = (acc > 0.0f) ? 1.0f : ((acc < 0.0f) ? -1.0f : 0.0f);
  float val = __fadd_rn(acc, __fmul_rn(s, __fmul_rn(noise, EPS_F)));

  if (K == 0) {
    dst[i] = val;                           // dst == out_layer (hop-0 ego)
    out_mean[i] = val;
  } else if (K == 1) {
    dst[i] = val;                           // ws ego buffer for hop 2
    out_mean[i] = __fadd_rn(out_mean[i], val);
  } else {
    out_mean[i] = __fadd_rn(out_mean[i], val) / 3.0f;
  }
}

// ---------------------------------------------------------------------------
// Launch
// ---------------------------------------------------------------------------
extern "C" void kernel_launch(void* const* d_in, const int* in_sizes, int n_in,
                              void* d_out, int out_size, void* d_ws, size_t ws_size,
                              hipStream_t stream) {
  const float* user_e = (const float*)d_in[0];
  const float* item_e = (const float*)d_in[1];
  const int*   rows   = (const int*)d_in[2];
  const int*   cols   = (const int*)d_in[3];
  const float* vals   = (const float*)d_in[4];

  float* out_mean  = (float*)d_out;           // [all_mean: 150000 x 64]
  float* out_layer = (float*)d_out + NELEM;   // [layer_embeddings] == hop-0 ego

  // workspace layout (~95 MB):
  //   staging 45,613,056 | counts 7,200,768 | base 7,200,768 |
  //   btot 12,288 | cnt 600,000 | off 600,000 | ego 38,400,000
  char* w = (char*)d_ws;
  ull*   staging = (ull*)w;                           // [0, 45,613,056)
  int*   counts  = (int*)(w + 45613056);              // 7,200,768
  int*   basep   = (int*)(w + 52813824);              // 7,200,768
  int*   btot    = (int*)(w + 60014592);              // 12,288
  int*   cnt     = (int*)(w + 60026880);              // 600,000
  int*   off     = (int*)(w + 60626880);              // 600,000
  float* ego     = (float*)(w + 61226880);            // 38,400,000

  // fold_in(key(42), k) = threefry((0,42),(0,k))
  unsigned hk0[3], hk1[3];
  for (int k = 0; k < 3; ++k)
    threefry2x32_fn(0u, 42u, 0u, (unsigned)k, &hk0[k], &hk1[k]);

  const int BT = 256;
  const unsigned row_blocks = N_NODES / 4;    // 37500 exact (4 rows/block)

  hist_kernel<<<NCHUNK, BT, 0, stream>>>(rows, counts);
  scan_kernel<<<NBUCK / BT, BT, 0, stream>>>(counts, basep, btot);
  scatter_kernel<<<NCHUNK, BT, 0, stream>>>(rows, cols, basep, staging);
  group_sort_kernel<<<NBUCK, BT, 0, stream>>>(vals, btot, staging, cnt, off);

  spmm_noise_kernel<0><<<row_blocks, BT, 0, stream>>>(
      staging, cnt, off, user_e, item_e, nullptr, out_layer, out_mean, hk0[0], hk1[0]);
  spmm_noise_kernel<1><<<row_blocks, BT, 0, stream>>>(
      staging, cnt, off, nullptr, nullptr, out_layer, ego, out_mean, hk0[1], hk1[1]);
  spmm_noise_kernel<2><<<row_blocks, BT, 0, stream>>>(
      staging, cnt, off, nullptr, nullptr, ego, nullptr, out_mean, hk0[2], hk1[2]);
}